// Round 10
// baseline (918.340 us; speedup 1.0000x reference)
//
#include <hip/hip_runtime.h>
#include <stdint.h>

// OctFormer block, MI355X gfx950.
// Pipeline: [fp8 data copy] [prep weights] -> CPE+LN1 -> QKV GEMM -> attn ->
//           proj GEMM(+resid+LN2 fused) -> FC1 GEMM(+gelu->fp8) -> FC2 fp8 GEMM(+resid)
// Residual stream x lives in d_out (f32). GEMMs: MFMA 16x16x32 (bf16 / fp8),
// 128-tiles, global_load_lds staging, XCD-aware block swizzle.
// CPE: wave handles 4 points; w_cpe staged in LDS; fp8 gather rows, batched loads.

static constexpr int NPT   = 131072;  // points
static constexpr int CC    = 256;     // channels
static constexpr int NWIN  = 4096;    // windows
static constexpr int NHEAD = 8;

using u16 = unsigned short;
using u32 = unsigned int;
using u8  = unsigned char;

typedef __bf16 bf16x8 __attribute__((ext_vector_type(8)));
typedef float  f32x4  __attribute__((ext_vector_type(4)));
typedef u32    u32x4  __attribute__((ext_vector_type(4)));
typedef u32    u32x2  __attribute__((ext_vector_type(2)));

__device__ __forceinline__ float b2f(u16 u) {
  union { float f; u32 i; } v; v.i = ((u32)u) << 16; return v.f;
}
__device__ __forceinline__ u16 f2b(float f) {  // RNE f32 -> bf16
  u32 x = __float_as_uint(f);
  return (u16)((x + 0x7fffu + ((x >> 16) & 1u)) >> 16);
}

// ---- OCP e4m3fn encode (RNE). |x| <= ~448 here, no saturation path needed.
__device__ __forceinline__ u8 f2fp8(float f) {
  const u32 s = (__float_as_uint(f) >> 24) & 0x80u;
  float a = fabsf(f);
  if (a >= 0.015625f) {                       // normal range
    u32 b = __float_as_uint(a);
    u32 rb = b + 0x7FFFFu + ((b >> 20) & 1u); // RNE on 3 mantissa bits
    u32 E = (rb >> 23) - 120u;                // exp bias 7
    return (u8)(s | (E << 3) | ((rb >> 20) & 7u));
  }
  int k = (int)rintf(a * 512.0f);             // denormal: multiples of 2^-9
  return (u8)(s | (u32)k);
}

// ---- OCP e4m3fn decode: byte J (compile-time) of dword d.
template <int J>
__device__ __forceinline__ float fp82f(u32 d) {
#if defined(__has_builtin)
#if __has_builtin(__builtin_amdgcn_cvt_f32_fp8)
  return __builtin_amdgcn_cvt_f32_fp8(d, J);
#else
  const u32 u = (d >> (8 * J)) & 0xFFu;
  const u32 e = (u >> 3) & 15u, m = u & 7u;
  float v = e ? __uint_as_float(((e + 120u) << 23) | (m << 20))
              : (float)m * 0.001953125f;
  return (u & 0x80u) ? -v : v;
#endif
#else
  const u32 u = (d >> (8 * J)) & 0xFFu;
  const u32 e = (u >> 3) & 15u, m = u & 7u;
  float v = e ? __uint_as_float(((e + 120u) << 23) | (m << 20))
              : (float)m * 0.001953125f;
  return (u & 0x80u) ? -v : v;
#endif
}

__device__ __forceinline__ void gload_lds16(const void* g, void* l) {
  using gptr_t = const __attribute__((address_space(1))) uint32_t*;
  using lptr_t = __attribute__((address_space(3))) uint32_t*;
  __builtin_amdgcn_global_load_lds((gptr_t)(uintptr_t)g,
                                   (lptr_t)(uint32_t)(uintptr_t)l, 16, 0, 0);
}

// ---------------- f32 -> fp8 e4m3 bulk convert ----------------
__global__ __launch_bounds__(256) void k_f2b8(const float* __restrict__ in,
                                              u8* __restrict__ out, int n4) {
  for (int i = blockIdx.x * 256 + threadIdx.x; i < n4; i += gridDim.x * 256) {
    float4 v = ((const float4*)in)[i];
    u32 o = (u32)f2fp8(v.x) | ((u32)f2fp8(v.y) << 8) |
            ((u32)f2fp8(v.z) << 16) | ((u32)f2fp8(v.w) << 24);
    ((u32*)out)[i] = o;
  }
}

// ---------------- all 4 weight transposes (+convert) in one launch -------------
// qkv/proj/fc1 -> bf16; fc2 -> fp8 e4m3 (consumed by fp8 MFMA in k_gemm8).
__global__ __launch_bounds__(256) void k_prep_w(
    const float* __restrict__ wqkv, const float* __restrict__ wproj,
    const float* __restrict__ wfc1, const float* __restrict__ wfc2,
    u16* __restrict__ oqkv, u16* __restrict__ oproj,
    u16* __restrict__ ofc1, u8* __restrict__ ofc2) {
  int i = blockIdx.x * 256 + threadIdx.x;
  if (i < 196608) {                       // w_qkv 256x768 -> [768][256]
    int c = i >> 8, r = i & 255; oqkv[i] = f2b(wqkv[r * 768 + c]);
  } else if (i < 262144) {                // w_proj 256x256
    i -= 196608; int c = i >> 8, r = i & 255; oproj[i] = f2b(wproj[r * 256 + c]);
  } else if (i < 524288) {                // w_fc1 256x1024 -> [1024][256]
    i -= 262144; int c = i >> 8, r = i & 255; ofc1[i] = f2b(wfc1[r * 1024 + c]);
  } else {                                // w_fc2 1024x256 -> [256][1024] fp8
    i -= 524288; int c = i >> 10, r = i & 1023; ofc2[i] = f2fp8(wfc2[r * 256 + c]);
  }
}

// ---------------- CPE gather + residual + LN1 (wave = 4 points) ----------------
// w_cpe staged in LDS once per block (kills the per-point 27x float4 L1 cost);
// each wave then processes 4 points: batched d[27] fp8 gathers + LDS w reads.
__global__ __launch_bounds__(256) void k_cpe_ln1(
    const float* __restrict__ data, const int* __restrict__ nbr,
    const u8* __restrict__ datab, const float* __restrict__ w_cpe,
    const float* __restrict__ bn_g, const float* __restrict__ bn_b,
    const float* __restrict__ n1_g, const float* __restrict__ n1_b,
    float* __restrict__ xo, u16* __restrict__ ho) {
  __shared__ __align__(16) float sW[27 * 256];
  const int tid = threadIdx.x;
  {
    const float4* src = (const float4*)w_cpe;
    float4* dst = (float4*)sW;
#pragma unroll
    for (int i = 0; i < 7; i++) {
      int idx = i * 256 + tid;
      if (idx < 27 * 64) dst[idx] = src[idx];
    }
  }
  __syncthreads();

  const int wv   = tid >> 6;
  const int lane = tid & 63;
  const int c0   = lane * 4;
  const int n0   = blockIdx.x * 16 + wv * 4;

  const float4 g4  = *(const float4*)(bn_g + c0);
  const float4 b4  = *(const float4*)(bn_b + c0);
  const float4 ng  = *(const float4*)(n1_g + c0);
  const float4 nb4 = *(const float4*)(n1_b + c0);

#pragma unroll 1
  for (int p = 0; p < 4; p++) {
    const int n = n0 + p;
    int myidx = 0;
    if (lane < 27) myidx = nbr[n * 27 + lane];

    u32 d[27];
#pragma unroll
    for (int j = 0; j < 27; j++) {
      const int idx = __builtin_amdgcn_readlane(myidx, j);
      d[j] = *(const u32*)(datab + (size_t)idx * CC + c0);
    }

    float a0 = 0.f, a1 = 0.f, a2 = 0.f, a3 = 0.f;
#pragma unroll
    for (int j = 0; j < 27; j++) {
      const float4 wj = *(const float4*)&sW[j * 256 + c0];
      a0 += fp82f<0>(d[j]) * wj.x;
      a1 += fp82f<1>(d[j]) * wj.y;
      a2 += fp82f<2>(d[j]) * wj.z;
      a3 += fp82f<3>(d[j]) * wj.w;
    }

    const float4 dv = *(const float4*)(data + (size_t)n * CC + c0);
    float x0 = dv.x + a0 * g4.x + b4.x;
    float x1 = dv.y + a1 * g4.y + b4.y;
    float x2 = dv.z + a2 * g4.z + b4.z;
    float x3 = dv.w + a3 * g4.w + b4.w;
    *(float4*)(xo + (size_t)n * CC + c0) = make_float4(x0, x1, x2, x3);

    float s  = x0 + x1 + x2 + x3;
    float s2 = x0 * x0 + x1 * x1 + x2 * x2 + x3 * x3;
#pragma unroll
    for (int m = 1; m <= 32; m <<= 1) { s += __shfl_xor(s, m); s2 += __shfl_xor(s2, m); }
    const float mean = s * (1.f / 256.f);
    const float var  = s2 * (1.f / 256.f) - mean * mean;
    const float inv  = rsqrtf(var + 1e-5f);

    u32x2 o;
    o[0] = (u32)f2b((x0 - mean) * inv * ng.x + nb4.x) |
           ((u32)f2b((x1 - mean) * inv * ng.y + nb4.y) << 16);
    o[1] = (u32)f2b((x2 - mean) * inv * ng.z + nb4.z) |
           ((u32)f2b((x3 - mean) * inv * ng.w + nb4.w) << 16);
    *(u32x2*)(ho + (size_t)n * CC + c0) = o;
  }
}

// ---------------- bf16 MFMA GEMM: C[M][ND] = A[M][KD] * Bt[ND][KD]^T -----------
// XCD-aware swizzle (nwg % 8 == 0 for all instantiations).
// EPI 0: out_bf16 = acc + bias
// EPI 2: out_fp8  = gelu_exact(acc + bias)   (outb reinterpreted as u8*)
template <int KD, int ND, int EPI>
__global__ __launch_bounds__(256) void k_gemm(const u16* __restrict__ A,
                                              const u16* __restrict__ Bt,
                                              const float* __restrict__ bias,
                                              u16* __restrict__ outb,
                                              float* __restrict__ outf) {
  __shared__ __align__(16) u16 As[128 * 64];
  __shared__ __align__(16) u16 Bs[128 * 64];
  const int tid = threadIdx.x;
  const int lane = tid & 63;
  const int wv = tid >> 6;
  const int wm = (wv >> 1) * 64;
  const int wn = (wv & 1) * 64;
  const int l15 = lane & 15;
  const int lhi = lane >> 4;

  const int gx = gridDim.x;
  const int bid = blockIdx.y * gx + blockIdx.x;
  const int cpx = (gx * gridDim.y) >> 3;
  const int swz = (bid & 7) * cpx + (bid >> 3);
  const int m0 = (swz / gx) * 128;
  const int n0 = (swz % gx) * 128;

  f32x4 acc[4][4] = {};

  for (int k0 = 0; k0 < KD; k0 += 64) {
#pragma unroll
    for (int i = 0; i < 4; i++) {
      const int off = i * 4096 + tid * 16;     // byte offset in 16KB tile
      const int row = off >> 7;                // 128B (=64 bf16) per row
      const int ke  = (off & 127) >> 1;        // element offset in K
      gload_lds16(A  + (size_t)(m0 + row) * KD + k0 + ke, (char*)As + off);
      gload_lds16(Bt + (size_t)(n0 + row) * KD + k0 + ke, (char*)Bs + off);
    }
    __syncthreads();
#pragma unroll
    for (int kk = 0; kk < 2; kk++) {
      bf16x8 fa[4], fb[4];
#pragma unroll
      for (int t = 0; t < 4; t++) {
        fa[t] = *(const bf16x8*)&As[(wm + t * 16 + l15) * 64 + kk * 32 + lhi * 8];
        fb[t] = *(const bf16x8*)&Bs[(wn + t * 16 + l15) * 64 + kk * 32 + lhi * 8];
      }
#pragma unroll
      for (int mi = 0; mi < 4; mi++)
#pragma unroll
        for (int ni = 0; ni < 4; ni++)
          acc[mi][ni] = __builtin_amdgcn_mfma_f32_16x16x32_bf16(fa[mi], fb[ni],
                                                                acc[mi][ni], 0, 0, 0);
    }
    __syncthreads();
  }

#pragma unroll
  for (int mi = 0; mi < 4; mi++) {
#pragma unroll
    for (int ni = 0; ni < 4; ni++) {
      const int col = n0 + wn + ni * 16 + l15;
      const float bc = bias[col];
#pragma unroll
      for (int r = 0; r < 4; r++) {
        const int row = m0 + wm + mi * 16 + lhi * 4 + r;
        const size_t o = (size_t)row * ND + col;
        float v = acc[mi][ni][r] + bc;
        if constexpr (EPI == 0) {
          outb[o] = f2b(v);
        } else {
          v = 0.5f * v * (1.0f + erff(v * 0.70710678118654752f));
          ((u8*)outb)[o] = f2fp8(v);
        }
      }
    }
  }
}

// ---------------- fp8 MFMA GEMM (FC2): x += A8[M][1024] * Bt8[256][1024]^T + b --
// Both operands fp8 e4m3 with identical fragment addressing (k-permutation
// cancels in the dot product). C/D layout is shape-determined (HW-verified).
__global__ __launch_bounds__(256) void k_gemm8(const u8* __restrict__ A,
                                               const u8* __restrict__ Bt,
                                               const float* __restrict__ bias,
                                               float* __restrict__ outf) {
  __shared__ __align__(16) u8 As[128 * 64];
  __shared__ __align__(16) u8 Bs[128 * 64];
  const int tid = threadIdx.x;
  const int lane = tid & 63;
  const int wv = tid >> 6;
  const int wm = (wv >> 1) * 64;
  const int wn = (wv & 1) * 64;
  const int l15 = lane & 15;
  const int lhi = lane >> 4;

  const int gx = gridDim.x;
  const int bid = blockIdx.y * gx + blockIdx.x;
  const int cpx = (gx * gridDim.y) >> 3;
  const int swz = (bid & 7) * cpx + (bid >> 3);
  const int m0 = (swz / gx) * 128;
  const int n0 = (swz % gx) * 128;

  f32x4 acc[4][4] = {};

  for (int k0 = 0; k0 < 1024; k0 += 64) {
#pragma unroll
    for (int i = 0; i < 2; i++) {
      const int off = i * 4096 + tid * 16;     // byte offset in 8KB tile
      const int row = off >> 6;                // 64B (=64 fp8) per row
      const int ke  = off & 63;
      gload_lds16(A  + (size_t)(m0 + row) * 1024 + k0 + ke, (char*)As + off);
      gload_lds16(Bt + (size_t)(n0 + row) * 1024 + k0 + ke, (char*)Bs + off);
    }
    __syncthreads();
#pragma unroll
    for (int kk = 0; kk < 2; kk++) {
      long fa[4], fb[4];
#pragma unroll
      for (int t = 0; t < 4; t++) {
        fa[t] = *(const long*)&As[(wm + t * 16 + l15) * 64 + kk * 32 + lhi * 8];
        fb[t] = *(const long*)&Bs[(wn + t * 16 + l15) * 64 + kk * 32 + lhi * 8];
      }
#pragma unroll
      for (int mi = 0; mi < 4; mi++)
#pragma unroll
        for (int ni = 0; ni < 4; ni++)
          acc[mi][ni] = __builtin_amdgcn_mfma_f32_16x16x32_fp8_fp8(fa[mi], fb[ni],
                                                                   acc[mi][ni], 0, 0, 0);
    }
    __syncthreads();
  }

#pragma unroll
  for (int mi = 0; mi < 4; mi++) {
#pragma unroll
    for (int ni = 0; ni < 4; ni++) {
      const int col = n0 + wn + ni * 16 + l15;
      const float bc = bias[col];
#pragma unroll
      for (int r = 0; r < 4; r++) {
        const int row = m0 + wm + mi * 16 + lhi * 4 + r;
        outf[(size_t)row * 256 + col] += acc[mi][ni][r] + bc;
      }
    }
  }
}

// ---------------- proj GEMM + residual + LN2 fused ----------------
__global__ __launch_bounds__(256) void k_proj_ln2(
    const u16* __restrict__ A, const u16* __restrict__ Bt,
    const float* __restrict__ bias, float* __restrict__ xo,
    const float* __restrict__ n2g, const float* __restrict__ n2b,
    u16* __restrict__ h2) {
  __shared__ __align__(16) u16 As[128 * 64];
  __shared__ __align__(16) u16 Bs[256 * 64];
  const int tid = threadIdx.x;
  const int lane = tid & 63;
  const int wv = tid >> 6;
  const int l15 = lane & 15;
  const int g = lane >> 4;
  const int m0 = blockIdx.x * 128;
  const int wm = wv * 32;

  f32x4 acc[2][16] = {};

  for (int k0 = 0; k0 < 256; k0 += 64) {
#pragma unroll
    for (int i = 0; i < 4; i++) {
      const int off = i * 4096 + tid * 16;
      const int row = off >> 7, ke = (off & 127) >> 1;
      gload_lds16(A + (size_t)(m0 + row) * 256 + k0 + ke, (char*)As + off);
    }
#pragma unroll
    for (int i = 0; i < 8; i++) {
      const int off = i * 4096 + tid * 16;
      const int row = off >> 7, ke = (off & 127) >> 1;
      gload_lds16(Bt + (size_t)row * 256 + k0 + ke, (char*)Bs + off);
    }
    __syncthreads();
#pragma unroll
    for (int kk = 0; kk < 2; kk++) {
      bf16x8 fa[2];
#pragma unroll
      for (int t = 0; t < 2; t++)
        fa[t] = *(const bf16x8*)&As[(wm + t * 16 + l15) * 64 + kk * 32 + g * 8];
#pragma unroll
      for (int ni = 0; ni < 16; ni++) {
        bf16x8 fb = *(const bf16x8*)&Bs[(ni * 16 + l15) * 64 + kk * 32 + g * 8];
#pragma unroll
        for (int mi = 0; mi < 2; mi++)
          acc[mi][ni] = __builtin_amdgcn_mfma_f32_16x16x32_bf16(fa[mi], fb,
                                                                acc[mi][ni], 0, 0, 0);
      }
    }
    __syncthreads();
  }

#pragma unroll
  for (int mi = 0; mi < 2; mi++) {
#pragma unroll
    for (int r = 0; r < 4; r++) {
      const int row = m0 + wm + mi * 16 + g * 4 + r;
      float v[16];
      float s = 0.f, s2 = 0.f;
#pragma unroll
      for (int ni = 0; ni < 16; ni++) {
        const int col = ni * 16 + l15;
        float t = acc[mi][ni][r] + bias[col] + xo[(size_t)row * 256 + col];
        v[ni] = t; s += t; s2 += t * t;
      }
#pragma unroll
      for (int m = 1; m <= 8; m <<= 1) { s += __shfl_xor(s, m); s2 += __shfl_xor(s2, m); }
      const float mean = s * (1.f / 256.f);
      const float var  = s2 * (1.f / 256.f) - mean * mean;
      const float inv  = rsqrtf(var + 1e-5f);
#pragma unroll
      for (int ni = 0; ni < 16; ni++) {
        const int col = ni * 16 + l15;
        xo[(size_t)row * 256 + col] = v[ni];
        h2[(size_t)row * 256 + col] = f2b((v[ni] - mean) * inv * n2g[col] + n2b[col]);
      }
    }
  }
}

// ---------------- windowed attention with RPE (MFMA version) ----------------
__global__ __launch_bounds__(512, 4) void k_attn(const u16* __restrict__ qkv,
                                                 const int* __restrict__ rel_pos,
                                                 const float* __restrict__ pmask,
                                                 const float* __restrict__ rpet,
                                                 u16* __restrict__ out) {
  constexpr int HS = 1288;                      // u16 per head region (2576 B)
  __shared__ __align__(16) u16 smem[24 * HS + 2448];
  u16* sQ = smem;
  u16* sK = smem + 8 * HS;                      // overlaid by O_lds [32][264] later
  u16* sV = smem + 16 * HS;                     // V^T per head: [d][p], rows 40 u16
  float* sT = (float*)(smem + 24 * HS);         // [8][153]

  const int tid = threadIdx.x;
  const int nw  = blockIdx.x;
  const int w32 = nw * 32;

  for (int i = tid; i < 1224; i += 512) {
    int h = i / 153, ix = i - h * 153;
    sT[i] = rpet[ix * 8 + h];
  }
#pragma unroll
  for (int j = 0; j < 4; j++) {
    int id  = j * 512 + tid;
    int mat = id >> 10;                         // 0 = Q, 1 = K (wave-uniform)
    int id1 = id & 1023;
    int h = id1 >> 7, q = (id1 >> 2) & 31, s = id1 & 3;
    u32x4 v = *(const u32x4*)(qkv + (size_t)(w32 + q) * 768 + mat * 256 + h * 32 + s * 8);
    u16* dst = (mat ? sK : sQ) + h * HS + q * 40 + s * 8;
    *(u32x4*)dst = v;
  }
#pragma unroll
  for (int j = 0; j < 2; j++) {
    int id = j * 512 + tid;
    int p = id >> 5, dc = id & 31;
    u32x4 v = *(const u32x4*)(qkv + (size_t)(w32 + p) * 768 + 512 + dc * 8);
    const u16* pv = (const u16*)&v;
#pragma unroll
    for (int jj = 0; jj < 8; jj++) {
      int d = dc * 8 + jj;
      sV[(d >> 5) * HS + (d & 31) * 40 + p] = pv[jj];
    }
  }
  __syncthreads();

  const int h = tid >> 6;
  const int lane = tid & 63;
  const int g = lane >> 4, c = lane & 15;
  const f32x4 zero = {0.f, 0.f, 0.f, 0.f};

  bf16x8 fq[2], fk[2];
#pragma unroll
  for (int t = 0; t < 2; t++) {
    fq[t] = *(const bf16x8*)&sQ[h * HS + (t * 16 + c) * 40 + g * 8];
    fk[t] = *(const bf16x8*)&sK[h * HS + (t * 16 + c) * 40 + g * 8];
  }
  f32x4 S[2][2];
#pragma unroll
  for (int qt = 0; qt < 2; qt++)
#pragma unroll
    for (int kt = 0; kt < 2; kt++)
      S[qt][kt] = __builtin_amdgcn_mfma_f32_16x16x32_bf16(fq[qt], fk[kt], zero, 0, 0, 0);

  const float sc = 0.17677669529663687f;  // 32^-0.5
#pragma unroll
  for (int qt = 0; qt < 2; qt++) {
#pragma unroll
    for (int r = 0; r < 4; r++) {
      const int q = qt * 16 + g * 4 + r;
      const int* rp = rel_pos + ((size_t)(w32 + q) * 32) * 3;
      const float* pm = pmask + (size_t)(w32 + q) * 32;
      float v[2];
#pragma unroll
      for (int kt = 0; kt < 2; kt++) {
        const int k = kt * 16 + c;
        int r0 = rp[k * 3], r1 = rp[k * 3 + 1], r2 = rp[k * 3 + 2];
        r0 = min(max(r0, -25), 25);
        r1 = min(max(r1, -25), 25);
        r2 = min(max(r2, -25), 25);
        const float b = sT[h * 153 + 25 + r0] + sT[h * 153 + 76 + r1] +
                        sT[h * 153 + 127 + r2] + pm[k];
        v[kt] = S[qt][kt][r] * sc + b;
      }
      float m = fmaxf(v[0], v[1]);
#pragma unroll
      for (int d = 1; d <= 8; d <<= 1) m = fmaxf(m, __shfl_xor(m, d));
      const float e0 = __expf(v[0] - m);
      const float e1 = __expf(v[1] - m);
      float ssum = e0 + e1;
#pragma unroll
      for (int d = 1; d <= 8; d <<= 1) ssum += __shfl_xor(ssum, d);
      const float inv = 1.0f / ssum;
      sQ[h * HS + q * 40 + c]      = f2b(e0 * inv);
      sQ[h * HS + q * 40 + 16 + c] = f2b(e1 * inv);
    }
  }
  __builtin_amdgcn_sched_barrier(0);  // P writes stay before P-fragment reads

  bf16x8 fp[2], fv[2];
#pragma unroll
  for (int t = 0; t < 2; t++) {
    fp[t] = *(const bf16x8*)&sQ[h * HS + (t * 16 + c) * 40 + g * 8];
    fv[t] = *(const bf16x8*)&sV[h * HS + (t * 16 + c) * 40 + g * 8];
  }
  f32x4 OT[2][2];
#pragma unroll
  for (int dt = 0; dt < 2; dt++)
#pragma unroll
    for (int qt = 0; qt < 2; qt++)
      OT[dt][qt] = __builtin_amdgcn_mfma_f32_16x16x32_bf16(fv[dt], fp[qt], zero, 0, 0, 0);

  __syncthreads();                     // all waves done reading K: reuse sK as O_lds
  u16* OL = sK;                        // [32 rows][264 u16]
#pragma unroll
  for (int dt = 0; dt < 2; dt++)
#pragma unroll
    for (int qt = 0; qt < 2; qt++)
#pragma unroll
      for (int r = 0; r < 4; r++) {
        const int d = dt * 16 + g * 4 + r, q = qt * 16 + c;
        OL[q * 264 + h * 32 + d] = f2b(OT[dt][qt][r]);
      }
  __syncthreads();

  {
    const int q = tid >> 4, ch = tid & 15;
    u32x4 w0 = *(const u32x4*)&OL[q * 264 + ch * 16];
    u32x4 w1 = *(const u32x4*)&OL[q * 264 + ch * 16 + 8];
    u16* ob = out + (size_t)(w32 + q) * 256 + ch * 16;
    *(u32x4*)ob = w0;
    *((u32x4*)ob + 1) = w1;
  }
}

extern "C" void kernel_launch(void* const* d_in, const int* in_sizes, int n_in,
                              void* d_out, int out_size, void* d_ws, size_t ws_size,
                              hipStream_t stream) {
  const float* data   = (const float*)d_in[0];
  const int*   nbr    = (const int*)d_in[1];
  const int*   relpos = (const int*)d_in[2];
  const float* pmask  = (const float*)d_in[3];
  const float* w_cpe  = (const float*)d_in[4];
  const float* bn_g   = (const float*)d_in[5];
  const float* bn_b   = (const float*)d_in[6];
  const float* n1_g   = (const float*)d_in[7];
  const float* n1_b   = (const float*)d_in[8];
  const float* w_qkv  = (const float*)d_in[9];
  const float* b_qkv  = (const float*)d_in[10];
  const float* w_proj = (const float*)d_in[11];
  const float* b_proj = (const float*)d_in[12];
  const float* rpet   = (const float*)d_in[13];
  const float* n2_g   = (const float*)d_in[14];
  const float* n2_b   = (const float*)d_in[15];
  const float* w_fc1  = (const float*)d_in[16];
  const float* b_fc1  = (const float*)d_in[17];
  const float* w_fc2  = (const float*)d_in[18];
  const float* b_fc2  = (const float*)d_in[19];
  float* xout = (float*)d_out;  // residual stream x lives in d_out (f32)

  char* pw = (char*)d_ws;
  u16* buf1 = (u16*)pw; pw += (size_t)NPT * 1024 * 2;  // fp8 data / qkv bf16 / hidden fp8
  u16* buf2 = (u16*)pw; pw += (size_t)NPT * 256 * 2;   // h / attn_out / h2
  u16* wqkvT = (u16*)pw; pw += 768 * 256 * 2;
  u16* wprojT = (u16*)pw; pw += 256 * 256 * 2;
  u16* wfc1T = (u16*)pw; pw += 1024 * 256 * 2;
  u8*  wfc2T8 = (u8*)pw; pw += 256 * 1024;
  u8* data8 = (u8*)buf1;  // 32 MB fp8 copy, consumed before buf1 is reused by QKV

  // prep: fp8 copy of data (for CPE gathers), transposed weights
  k_f2b8<<<2048, 256, 0, stream>>>(data, data8, NPT * 256 / 4);
  k_prep_w<<<3072, 256, 0, stream>>>(w_qkv, w_proj, w_fc1, w_fc2,
                                     wqkvT, wprojT, wfc1T, wfc2T8);

  // CPE + residual + LN1:  x -> d_out(f32), h -> buf2(bf16)
  k_cpe_ln1<<<NPT / 16, 256, 0, stream>>>(data, nbr, data8, w_cpe, bn_g, bn_b,
                                          n1_g, n1_b, xout, buf2);
  // QKV = h @ w_qkv + b  -> buf1 (bf16, N x 768)
  k_gemm<256, 768, 0><<<dim3(6, 1024), 256, 0, stream>>>(buf2, wqkvT, b_qkv, buf1, nullptr);
  // attention -> buf2 (bf16, N x 256)
  k_attn<<<NWIN, 512, 0, stream>>>(buf1, relpos, pmask, rpet, buf2);
  // x += attn_out @ w_proj + b; h2 = LN2(x) -> buf2
  k_proj_ln2<<<1024, 256, 0, stream>>>(buf2, wprojT, b_proj, xout, n2_g, n2_b, buf2);
  // hidden = gelu(h2 @ w_fc1 + b) -> buf1 (fp8, N x 1024)
  k_gemm<256, 1024, 2><<<dim3(8, 1024), 256, 0, stream>>>(buf2, wfc1T, b_fc1, buf1, nullptr);
  // x += hidden @ w_fc2 + b   (fp8 MFMA; final output in d_out)
  k_gemm8<<<dim3(2, 1024), 256, 0, stream>>>((u8*)buf1, wfc2T8, b_fc2, xout);
}

// Round 11
// 889.145 us; speedup vs baseline: 1.0328x; 1.0328x over previous
//
#include <hip/hip_runtime.h>
#include <stdint.h>

// OctFormer block, MI355X gfx950.
// Pipeline: [fp8 data copy] [prep weights] -> CPE+LN1 -> QKV GEMM -> attn ->
//           proj GEMM(+resid+LN2 fused) -> FC1 GEMM(+gelu) -> FC2 GEMM(+resid -> d_out)
// Residual stream x lives in d_out (f32). GEMMs: bf16 MFMA 16x16x32, 128-tiles,
// global_load_lds staging, XCD-aware block swizzle.
// CPE: wave handles 4 points; w_cpe staged in LDS as bf16 (13.8 KB); fp8 gather
// rows with batched d[27] loads.

static constexpr int NPT   = 131072;  // points
static constexpr int CC    = 256;     // channels
static constexpr int NWIN  = 4096;    // windows
static constexpr int NHEAD = 8;

using u16 = unsigned short;
using u32 = unsigned int;
using u8  = unsigned char;

typedef __bf16 bf16x8 __attribute__((ext_vector_type(8)));
typedef float  f32x4  __attribute__((ext_vector_type(4)));
typedef u32    u32x4  __attribute__((ext_vector_type(4)));
typedef u32    u32x2  __attribute__((ext_vector_type(2)));

__device__ __forceinline__ float b2f(u16 u) {
  union { float f; u32 i; } v; v.i = ((u32)u) << 16; return v.f;
}
__device__ __forceinline__ u16 f2b(float f) {  // RNE f32 -> bf16
  u32 x = __float_as_uint(f);
  return (u16)((x + 0x7fffu + ((x >> 16) & 1u)) >> 16);
}

// ---- OCP e4m3fn encode (RNE). Inputs here |x| <= ~6, no saturation path.
__device__ __forceinline__ u8 f2fp8(float f) {
  const u32 s = (__float_as_uint(f) >> 24) & 0x80u;
  float a = fabsf(f);
  if (a >= 0.015625f) {                       // normal range
    u32 b = __float_as_uint(a);
    u32 rb = b + 0x7FFFFu + ((b >> 20) & 1u); // RNE on 3 mantissa bits
    u32 E = (rb >> 23) - 120u;                // exp bias 7
    return (u8)(s | (E << 3) | ((rb >> 20) & 7u));
  }
  int k = (int)rintf(a * 512.0f);             // denormal: multiples of 2^-9
  return (u8)(s | (u32)k);
}

// ---- OCP e4m3fn decode: byte J (compile-time) of dword d.
template <int J>
__device__ __forceinline__ float fp82f(u32 d) {
#if defined(__has_builtin)
#if __has_builtin(__builtin_amdgcn_cvt_f32_fp8)
  return __builtin_amdgcn_cvt_f32_fp8(d, J);
#else
  const u32 u = (d >> (8 * J)) & 0xFFu;
  const u32 e = (u >> 3) & 15u, m = u & 7u;
  float v = e ? __uint_as_float(((e + 120u) << 23) | (m << 20))
              : (float)m * 0.001953125f;
  return (u & 0x80u) ? -v : v;
#endif
#else
  const u32 u = (d >> (8 * J)) & 0xFFu;
  const u32 e = (u >> 3) & 15u, m = u & 7u;
  float v = e ? __uint_as_float(((e + 120u) << 23) | (m << 20))
              : (float)m * 0.001953125f;
  return (u & 0x80u) ? -v : v;
#endif
}

__device__ __forceinline__ void gload_lds16(const void* g, void* l) {
  using gptr_t = const __attribute__((address_space(1))) uint32_t*;
  using lptr_t = __attribute__((address_space(3))) uint32_t*;
  __builtin_amdgcn_global_load_lds((gptr_t)(uintptr_t)g,
                                   (lptr_t)(uint32_t)(uintptr_t)l, 16, 0, 0);
}

// ---------------- f32 -> fp8 e4m3 bulk convert ----------------
__global__ __launch_bounds__(256) void k_f2b8(const float* __restrict__ in,
                                              u8* __restrict__ out, int n4) {
  for (int i = blockIdx.x * 256 + threadIdx.x; i < n4; i += gridDim.x * 256) {
    float4 v = ((const float4*)in)[i];
    u32 o = (u32)f2fp8(v.x) | ((u32)f2fp8(v.y) << 8) |
            ((u32)f2fp8(v.z) << 16) | ((u32)f2fp8(v.w) << 24);
    ((u32*)out)[i] = o;
  }
}

// ---------------- all 4 weight transposes (+bf16 convert) in one launch --------
__global__ __launch_bounds__(256) void k_prep_w(
    const float* __restrict__ wqkv, const float* __restrict__ wproj,
    const float* __restrict__ wfc1, const float* __restrict__ wfc2,
    u16* __restrict__ oqkv, u16* __restrict__ oproj,
    u16* __restrict__ ofc1, u16* __restrict__ ofc2) {
  int i = blockIdx.x * 256 + threadIdx.x;
  if (i < 196608) {                       // w_qkv 256x768 -> [768][256]
    int c = i >> 8, r = i & 255; oqkv[i] = f2b(wqkv[r * 768 + c]);
  } else if (i < 262144) {                // w_proj 256x256
    i -= 196608; int c = i >> 8, r = i & 255; oproj[i] = f2b(wproj[r * 256 + c]);
  } else if (i < 524288) {                // w_fc1 256x1024 -> [1024][256]
    i -= 262144; int c = i >> 8, r = i & 255; ofc1[i] = f2b(wfc1[r * 1024 + c]);
  } else {                                // w_fc2 1024x256 -> [256][1024]
    i -= 524288; int c = i >> 10, r = i & 1023; ofc2[i] = f2b(wfc2[r * 256 + c]);
  }
}

// ---------------- CPE gather + residual + LN1 (wave = 4 points) ----------------
// w_cpe staged in LDS as bf16 (13.8 KB -> no LDS occupancy limit); batched d[27]
// fp8 gathers. Lane owns channels [4*lane, 4*lane+4).
__global__ __launch_bounds__(256) void k_cpe_ln1(
    const float* __restrict__ data, const int* __restrict__ nbr,
    const u8* __restrict__ datab, const float* __restrict__ w_cpe,
    const float* __restrict__ bn_g, const float* __restrict__ bn_b,
    const float* __restrict__ n1_g, const float* __restrict__ n1_b,
    float* __restrict__ xo, u16* __restrict__ ho) {
  __shared__ __align__(16) u16 sW[27 * 256];
  const int tid = threadIdx.x;
  // stage 6912 bf16 = 864 x 16B chunks
  for (int i = tid; i < 864; i += 256) {
    float4 a = ((const float4*)w_cpe)[i * 2];
    float4 b = ((const float4*)w_cpe)[i * 2 + 1];
    u32x4 o;
    o[0] = (u32)f2b(a.x) | ((u32)f2b(a.y) << 16);
    o[1] = (u32)f2b(a.z) | ((u32)f2b(a.w) << 16);
    o[2] = (u32)f2b(b.x) | ((u32)f2b(b.y) << 16);
    o[3] = (u32)f2b(b.z) | ((u32)f2b(b.w) << 16);
    ((u32x4*)sW)[i] = o;
  }
  __syncthreads();

  const int wv   = tid >> 6;
  const int lane = tid & 63;
  const int c0   = lane * 4;
  const int n0   = blockIdx.x * 16 + wv * 4;

  const float4 g4  = *(const float4*)(bn_g + c0);
  const float4 b4  = *(const float4*)(bn_b + c0);
  const float4 ng  = *(const float4*)(n1_g + c0);
  const float4 nb4 = *(const float4*)(n1_b + c0);

#pragma unroll 1
  for (int p = 0; p < 4; p++) {
    const int n = n0 + p;
    int myidx = 0;
    if (lane < 27) myidx = nbr[n * 27 + lane];

    u32 d[27];
#pragma unroll
    for (int j = 0; j < 27; j++) {
      const int idx = __builtin_amdgcn_readlane(myidx, j);
      d[j] = *(const u32*)(datab + (size_t)idx * CC + c0);
    }

    float a0 = 0.f, a1 = 0.f, a2 = 0.f, a3 = 0.f;
#pragma unroll
    for (int j = 0; j < 27; j++) {
      const u32x2 wp = *(const u32x2*)&sW[j * 256 + c0];
      a0 += fp82f<0>(d[j]) * b2f((u16)(wp[0] & 0xffff));
      a1 += fp82f<1>(d[j]) * b2f((u16)(wp[0] >> 16));
      a2 += fp82f<2>(d[j]) * b2f((u16)(wp[1] & 0xffff));
      a3 += fp82f<3>(d[j]) * b2f((u16)(wp[1] >> 16));
    }

    const float4 dv = *(const float4*)(data + (size_t)n * CC + c0);
    float x0 = dv.x + a0 * g4.x + b4.x;
    float x1 = dv.y + a1 * g4.y + b4.y;
    float x2 = dv.z + a2 * g4.z + b4.z;
    float x3 = dv.w + a3 * g4.w + b4.w;
    *(float4*)(xo + (size_t)n * CC + c0) = make_float4(x0, x1, x2, x3);

    float s  = x0 + x1 + x2 + x3;
    float s2 = x0 * x0 + x1 * x1 + x2 * x2 + x3 * x3;
#pragma unroll
    for (int m = 1; m <= 32; m <<= 1) { s += __shfl_xor(s, m); s2 += __shfl_xor(s2, m); }
    const float mean = s * (1.f / 256.f);
    const float var  = s2 * (1.f / 256.f) - mean * mean;
    const float inv  = rsqrtf(var + 1e-5f);

    u32x2 o;
    o[0] = (u32)f2b((x0 - mean) * inv * ng.x + nb4.x) |
           ((u32)f2b((x1 - mean) * inv * ng.y + nb4.y) << 16);
    o[1] = (u32)f2b((x2 - mean) * inv * ng.z + nb4.z) |
           ((u32)f2b((x3 - mean) * inv * ng.w + nb4.w) << 16);
    *(u32x2*)(ho + (size_t)n * CC + c0) = o;
  }
}

// ---------------- bf16 MFMA GEMM: C[M][ND] = A[M][KD] * Bt[ND][KD]^T -----------
// XCD-aware swizzle (nwg % 8 == 0 for all instantiations).
// EPI 0: out_bf16 = acc + bias
// EPI 1: out_f32 += acc + bias            (residual accumulate)
// EPI 2: out_bf16 = gelu_exact(acc + bias)
template <int KD, int ND, int EPI>
__global__ __launch_bounds__(256) void k_gemm(const u16* __restrict__ A,
                                              const u16* __restrict__ Bt,
                                              const float* __restrict__ bias,
                                              u16* __restrict__ outb,
                                              float* __restrict__ outf) {
  __shared__ __align__(16) u16 As[128 * 64];
  __shared__ __align__(16) u16 Bs[128 * 64];
  const int tid = threadIdx.x;
  const int lane = tid & 63;
  const int wv = tid >> 6;
  const int wm = (wv >> 1) * 64;
  const int wn = (wv & 1) * 64;
  const int l15 = lane & 15;
  const int lhi = lane >> 4;

  const int gx = gridDim.x;
  const int bid = blockIdx.y * gx + blockIdx.x;
  const int cpx = (gx * gridDim.y) >> 3;
  const int swz = (bid & 7) * cpx + (bid >> 3);
  const int m0 = (swz / gx) * 128;
  const int n0 = (swz % gx) * 128;

  f32x4 acc[4][4] = {};

  for (int k0 = 0; k0 < KD; k0 += 64) {
#pragma unroll
    for (int i = 0; i < 4; i++) {
      const int off = i * 4096 + tid * 16;     // byte offset in 16KB tile
      const int row = off >> 7;                // 128B (=64 bf16) per row
      const int ke  = (off & 127) >> 1;        // element offset in K
      gload_lds16(A  + (size_t)(m0 + row) * KD + k0 + ke, (char*)As + off);
      gload_lds16(Bt + (size_t)(n0 + row) * KD + k0 + ke, (char*)Bs + off);
    }
    __syncthreads();
#pragma unroll
    for (int kk = 0; kk < 2; kk++) {
      bf16x8 fa[4], fb[4];
#pragma unroll
      for (int t = 0; t < 4; t++) {
        fa[t] = *(const bf16x8*)&As[(wm + t * 16 + l15) * 64 + kk * 32 + lhi * 8];
        fb[t] = *(const bf16x8*)&Bs[(wn + t * 16 + l15) * 64 + kk * 32 + lhi * 8];
      }
#pragma unroll
      for (int mi = 0; mi < 4; mi++)
#pragma unroll
        for (int ni = 0; ni < 4; ni++)
          acc[mi][ni] = __builtin_amdgcn_mfma_f32_16x16x32_bf16(fa[mi], fb[ni],
                                                                acc[mi][ni], 0, 0, 0);
    }
    __syncthreads();
  }

#pragma unroll
  for (int mi = 0; mi < 4; mi++) {
#pragma unroll
    for (int ni = 0; ni < 4; ni++) {
      const int col = n0 + wn + ni * 16 + l15;
      const float bc = bias[col];
#pragma unroll
      for (int r = 0; r < 4; r++) {
        const int row = m0 + wm + mi * 16 + lhi * 4 + r;
        const size_t o = (size_t)row * ND + col;
        float v = acc[mi][ni][r] + bc;
        if constexpr (EPI == 0) {
          outb[o] = f2b(v);
        } else if constexpr (EPI == 1) {
          outf[o] += v;
        } else {
          v = 0.5f * v * (1.0f + erff(v * 0.70710678118654752f));
          outb[o] = f2b(v);
        }
      }
    }
  }
}

// ---------------- proj GEMM + residual + LN2 fused ----------------
__global__ __launch_bounds__(256) void k_proj_ln2(
    const u16* __restrict__ A, const u16* __restrict__ Bt,
    const float* __restrict__ bias, float* __restrict__ xo,
    const float* __restrict__ n2g, const float* __restrict__ n2b,
    u16* __restrict__ h2) {
  __shared__ __align__(16) u16 As[128 * 64];
  __shared__ __align__(16) u16 Bs[256 * 64];
  const int tid = threadIdx.x;
  const int lane = tid & 63;
  const int wv = tid >> 6;
  const int l15 = lane & 15;
  const int g = lane >> 4;
  const int m0 = blockIdx.x * 128;
  const int wm = wv * 32;

  f32x4 acc[2][16] = {};

  for (int k0 = 0; k0 < 256; k0 += 64) {
#pragma unroll
    for (int i = 0; i < 4; i++) {
      const int off = i * 4096 + tid * 16;
      const int row = off >> 7, ke = (off & 127) >> 1;
      gload_lds16(A + (size_t)(m0 + row) * 256 + k0 + ke, (char*)As + off);
    }
#pragma unroll
    for (int i = 0; i < 8; i++) {
      const int off = i * 4096 + tid * 16;
      const int row = off >> 7, ke = (off & 127) >> 1;
      gload_lds16(Bt + (size_t)row * 256 + k0 + ke, (char*)Bs + off);
    }
    __syncthreads();
#pragma unroll
    for (int kk = 0; kk < 2; kk++) {
      bf16x8 fa[2];
#pragma unroll
      for (int t = 0; t < 2; t++)
        fa[t] = *(const bf16x8*)&As[(wm + t * 16 + l15) * 64 + kk * 32 + g * 8];
#pragma unroll
      for (int ni = 0; ni < 16; ni++) {
        bf16x8 fb = *(const bf16x8*)&Bs[(ni * 16 + l15) * 64 + kk * 32 + g * 8];
#pragma unroll
        for (int mi = 0; mi < 2; mi++)
          acc[mi][ni] = __builtin_amdgcn_mfma_f32_16x16x32_bf16(fa[mi], fb,
                                                                acc[mi][ni], 0, 0, 0);
      }
    }
    __syncthreads();
  }

#pragma unroll
  for (int mi = 0; mi < 2; mi++) {
#pragma unroll
    for (int r = 0; r < 4; r++) {
      const int row = m0 + wm + mi * 16 + g * 4 + r;
      float v[16];
      float s = 0.f, s2 = 0.f;
#pragma unroll
      for (int ni = 0; ni < 16; ni++) {
        const int col = ni * 16 + l15;
        float t = acc[mi][ni][r] + bias[col] + xo[(size_t)row * 256 + col];
        v[ni] = t; s += t; s2 += t * t;
      }
#pragma unroll
      for (int m = 1; m <= 8; m <<= 1) { s += __shfl_xor(s, m); s2 += __shfl_xor(s2, m); }
      const float mean = s * (1.f / 256.f);
      const float var  = s2 * (1.f / 256.f) - mean * mean;
      const float inv  = rsqrtf(var + 1e-5f);
#pragma unroll
      for (int ni = 0; ni < 16; ni++) {
        const int col = ni * 16 + l15;
        xo[(size_t)row * 256 + col] = v[ni];
        h2[(size_t)row * 256 + col] = f2b((v[ni] - mean) * inv * n2g[col] + n2b[col]);
      }
    }
  }
}

// ---------------- windowed attention with RPE (MFMA version) ----------------
__global__ __launch_bounds__(512, 4) void k_attn(const u16* __restrict__ qkv,
                                                 const int* __restrict__ rel_pos,
                                                 const float* __restrict__ pmask,
                                                 const float* __restrict__ rpet,
                                                 u16* __restrict__ out) {
  constexpr int HS = 1288;                      // u16 per head region (2576 B)
  __shared__ __align__(16) u16 smem[24 * HS + 2448];
  u16* sQ = smem;
  u16* sK = smem + 8 * HS;                      // overlaid by O_lds [32][264] later
  u16* sV = smem + 16 * HS;                     // V^T per head: [d][p], rows 40 u16
  float* sT = (float*)(smem + 24 * HS);         // [8][153]

  const int tid = threadIdx.x;
  const int nw  = blockIdx.x;
  const int w32 = nw * 32;

  for (int i = tid; i < 1224; i += 512) {
    int h = i / 153, ix = i - h * 153;
    sT[i] = rpet[ix * 8 + h];
  }
#pragma unroll
  for (int j = 0; j < 4; j++) {
    int id  = j * 512 + tid;
    int mat = id >> 10;                         // 0 = Q, 1 = K (wave-uniform)
    int id1 = id & 1023;
    int h = id1 >> 7, q = (id1 >> 2) & 31, s = id1 & 3;
    u32x4 v = *(const u32x4*)(qkv + (size_t)(w32 + q) * 768 + mat * 256 + h * 32 + s * 8);
    u16* dst = (mat ? sK : sQ) + h * HS + q * 40 + s * 8;
    *(u32x4*)dst = v;
  }
#pragma unroll
  for (int j = 0; j < 2; j++) {
    int id = j * 512 + tid;
    int p = id >> 5, dc = id & 31;
    u32x4 v = *(const u32x4*)(qkv + (size_t)(w32 + p) * 768 + 512 + dc * 8);
    const u16* pv = (const u16*)&v;
#pragma unroll
    for (int jj = 0; jj < 8; jj++) {
      int d = dc * 8 + jj;
      sV[(d >> 5) * HS + (d & 31) * 40 + p] = pv[jj];
    }
  }
  __syncthreads();

  const int h = tid >> 6;
  const int lane = tid & 63;
  const int g = lane >> 4, c = lane & 15;
  const f32x4 zero = {0.f, 0.f, 0.f, 0.f};

  bf16x8 fq[2], fk[2];
#pragma unroll
  for (int t = 0; t < 2; t++) {
    fq[t] = *(const bf16x8*)&sQ[h * HS + (t * 16 + c) * 40 + g * 8];
    fk[t] = *(const bf16x8*)&sK[h * HS + (t * 16 + c) * 40 + g * 8];
  }
  f32x4 S[2][2];
#pragma unroll
  for (int qt = 0; qt < 2; qt++)
#pragma unroll
    for (int kt = 0; kt < 2; kt++)
      S[qt][kt] = __builtin_amdgcn_mfma_f32_16x16x32_bf16(fq[qt], fk[kt], zero, 0, 0, 0);

  const float sc = 0.17677669529663687f;  // 32^-0.5
#pragma unroll
  for (int qt = 0; qt < 2; qt++) {
#pragma unroll
    for (int r = 0; r < 4; r++) {
      const int q = qt * 16 + g * 4 + r;
      const int* rp = rel_pos + ((size_t)(w32 + q) * 32) * 3;
      const float* pm = pmask + (size_t)(w32 + q) * 32;
      float v[2];
#pragma unroll
      for (int kt = 0; kt < 2; kt++) {
        const int k = kt * 16 + c;
        int r0 = rp[k * 3], r1 = rp[k * 3 + 1], r2 = rp[k * 3 + 2];
        r0 = min(max(r0, -25), 25);
        r1 = min(max(r1, -25), 25);
        r2 = min(max(r2, -25), 25);
        const float b = sT[h * 153 + 25 + r0] + sT[h * 153 + 76 + r1] +
                        sT[h * 153 + 127 + r2] + pm[k];
        v[kt] = S[qt][kt][r] * sc + b;
      }
      float m = fmaxf(v[0], v[1]);
#pragma unroll
      for (int d = 1; d <= 8; d <<= 1) m = fmaxf(m, __shfl_xor(m, d));
      const float e0 = __expf(v[0] - m);
      const float e1 = __expf(v[1] - m);
      float ssum = e0 + e1;
#pragma unroll
      for (int d = 1; d <= 8; d <<= 1) ssum += __shfl_xor(ssum, d);
      const float inv = 1.0f / ssum;
      sQ[h * HS + q * 40 + c]      = f2b(e0 * inv);
      sQ[h * HS + q * 40 + 16 + c] = f2b(e1 * inv);
    }
  }
  __builtin_amdgcn_sched_barrier(0);  // P writes stay before P-fragment reads

  bf16x8 fp[2], fv[2];
#pragma unroll
  for (int t = 0; t < 2; t++) {
    fp[t] = *(const bf16x8*)&sQ[h * HS + (t * 16 + c) * 40 + g * 8];
    fv[t] = *(const bf16x8*)&sV[h * HS + (t * 16 + c) * 40 + g * 8];
  }
  f32x4 OT[2][2];
#pragma unroll
  for (int dt = 0; dt < 2; dt++)
#pragma unroll
    for (int qt = 0; qt < 2; qt++)
      OT[dt][qt] = __builtin_amdgcn_mfma_f32_16x16x32_bf16(fv[dt], fp[qt], zero, 0, 0, 0);

  __syncthreads();                     // all waves done reading K: reuse sK as O_lds
  u16* OL = sK;                        // [32 rows][264 u16]
#pragma unroll
  for (int dt = 0; dt < 2; dt++)
#pragma unroll
    for (int qt = 0; qt < 2; qt++)
#pragma unroll
      for (int r = 0; r < 4; r++) {
        const int d = dt * 16 + g * 4 + r, q = qt * 16 + c;
        OL[q * 264 + h * 32 + d] = f2b(OT[dt][qt][r]);
      }
  __syncthreads();

  {
    const int q = tid >> 4, ch = tid & 15;
    u32x4 w0 = *(const u32x4*)&OL[q * 264 + ch * 16];
    u32x4 w1 = *(const u32x4*)&OL[q * 264 + ch * 16 + 8];
    u16* ob = out + (size_t)(w32 + q) * 256 + ch * 16;
    *(u32x4*)ob = w0;
    *((u32x4*)ob + 1) = w1;
  }
}

extern "C" void kernel_launch(void* const* d_in, const int* in_sizes, int n_in,
                              void* d_out, int out_size, void* d_ws, size_t ws_size,
                              hipStream_t stream) {
  const float* data   = (const float*)d_in[0];
  const int*   nbr    = (const int*)d_in[1];
  const int*   relpos = (const int*)d_in[2];
  const float* pmask  = (const float*)d_in[3];
  const float* w_cpe  = (const float*)d_in[4];
  const float* bn_g   = (const float*)d_in[5];
  const float* bn_b   = (const float*)d_in[6];
  const float* n1_g   = (const float*)d_in[7];
  const float* n1_b   = (const float*)d_in[8];
  const float* w_qkv  = (const float*)d_in[9];
  const float* b_qkv  = (const float*)d_in[10];
  const float* w_proj = (const float*)d_in[11];
  const float* b_proj = (const float*)d_in[12];
  const float* rpet   = (const float*)d_in[13];
  const float* n2_g   = (const float*)d_in[14];
  const float* n2_b   = (const float*)d_in[15];
  const float* w_fc1  = (const float*)d_in[16];
  const float* b_fc1  = (const float*)d_in[17];
  const float* w_fc2  = (const float*)d_in[18];
  const float* b_fc2  = (const float*)d_in[19];
  float* xout = (float*)d_out;  // residual stream x lives in d_out (f32)

  char* pw = (char*)d_ws;
  u16* buf1 = (u16*)pw; pw += (size_t)NPT * 1024 * 2;  // fp8 data / qkv / hidden bf16
  u16* buf2 = (u16*)pw; pw += (size_t)NPT * 256 * 2;   // h / attn_out / h2
  u16* wqkvT = (u16*)pw; pw += 768 * 256 * 2;
  u16* wprojT = (u16*)pw; pw += 256 * 256 * 2;
  u16* wfc1T = (u16*)pw; pw += 1024 * 256 * 2;
  u16* wfc2T = (u16*)pw; pw += 256 * 1024 * 2;
  u8* data8 = (u8*)buf1;  // 32 MB fp8 copy, consumed before buf1 is reused by QKV

  // prep: fp8 copy of data (for CPE gathers), transposed bf16 weights
  k_f2b8<<<2048, 256, 0, stream>>>(data, data8, NPT * 256 / 4);
  k_prep_w<<<3072, 256, 0, stream>>>(w_qkv, w_proj, w_fc1, w_fc2,
                                     wqkvT, wprojT, wfc1T, wfc2T);

  // CPE + residual + LN1:  x -> d_out(f32), h -> buf2(bf16)
  k_cpe_ln1<<<NPT / 16, 256, 0, stream>>>(data, nbr, data8, w_cpe, bn_g, bn_b,
                                          n1_g, n1_b, xout, buf2);
  // QKV = h @ w_qkv + b  -> buf1 (bf16, N x 768)
  k_gemm<256, 768, 0><<<dim3(6, 1024), 256, 0, stream>>>(buf2, wqkvT, b_qkv, buf1, nullptr);
  // attention -> buf2 (bf16, N x 256)
  k_attn<<<NWIN, 512, 0, stream>>>(buf1, relpos, pmask, rpet, buf2);
  // x += attn_out @ w_proj + b; h2 = LN2(x) -> buf2
  k_proj_ln2<<<1024, 256, 0, stream>>>(buf2, wprojT, b_proj, xout, n2_g, n2_b, buf2);
  // hidden = gelu(h2 @ w_fc1 + b) -> buf1 (bf16, N x 1024)
  k_gemm<256, 1024, 2><<<dim3(8, 1024), 256, 0, stream>>>(buf2, wfc1T, b_fc1, buf1, nullptr);
  // x += hidden @ w_fc2 + b   (final output in d_out)
  k_gemm<1024, 256, 1><<<dim3(2, 1024), 256, 0, stream>>>(buf1, wfc2T, b_fc2, nullptr, xout);
}

// Round 13
// 884.181 us; speedup vs baseline: 1.0386x; 1.0056x over previous
//
#include <hip/hip_runtime.h>
#include <stdint.h>

// OctFormer block, MI355X gfx950.
// Pipeline: [fp8 data copy] [prep weights] -> CPE+LN1 -> QKV GEMM -> attn ->
//           proj GEMM(+resid+LN2 fused) -> FC1 GEMM(+gelu) -> FC2 GEMM(+resid -> d_out)
// Residual stream x lives in d_out (f32). GEMMs: bf16 MFMA 16x16x32, 128-tiles,
// global_load_lds staging, XCD-aware block swizzle, LDS-staged coalesced C-write
// (EPI0/EPI2). CPE: wave = 4 points, w_cpe in LDS (bf16), batched fp8 gathers.

static constexpr int NPT   = 131072;  // points
static constexpr int CC    = 256;     // channels
static constexpr int NWIN  = 4096;    // windows
static constexpr int NHEAD = 8;

using u16 = unsigned short;
using u32 = unsigned int;
using u8  = unsigned char;

typedef __bf16 bf16x8 __attribute__((ext_vector_type(8)));
typedef float  f32x4  __attribute__((ext_vector_type(4)));
typedef u32    u32x4  __attribute__((ext_vector_type(4)));
typedef u32    u32x2  __attribute__((ext_vector_type(2)));

__device__ __forceinline__ float b2f(u16 u) {
  union { float f; u32 i; } v; v.i = ((u32)u) << 16; return v.f;
}
__device__ __forceinline__ u16 f2b(float f) {  // RNE f32 -> bf16
  u32 x = __float_as_uint(f);
  return (u16)((x + 0x7fffu + ((x >> 16) & 1u)) >> 16);
}

// ---- OCP e4m3fn encode (RNE). Inputs here |x| <= ~6, no saturation path.
__device__ __forceinline__ u8 f2fp8(float f) {
  const u32 s = (__float_as_uint(f) >> 24) & 0x80u;
  float a = fabsf(f);
  if (a >= 0.015625f) {                       // normal range
    u32 b = __float_as_uint(a);
    u32 rb = b + 0x7FFFFu + ((b >> 20) & 1u); // RNE on 3 mantissa bits
    u32 E = (rb >> 23) - 120u;                // exp bias 7
    return (u8)(s | (E << 3) | ((rb >> 20) & 7u));
  }
  int k = (int)rintf(a * 512.0f);             // denormal: multiples of 2^-9
  return (u8)(s | (u32)k);
}

// ---- OCP e4m3fn decode: byte J (compile-time) of dword d.
template <int J>
__device__ __forceinline__ float fp82f(u32 d) {
#if defined(__has_builtin)
#if __has_builtin(__builtin_amdgcn_cvt_f32_fp8)
  return __builtin_amdgcn_cvt_f32_fp8(d, J);
#else
  const u32 u = (d >> (8 * J)) & 0xFFu;
  const u32 e = (u >> 3) & 15u, m = u & 7u;
  float v = e ? __uint_as_float(((e + 120u) << 23) | (m << 20))
              : (float)m * 0.001953125f;
  return (u & 0x80u) ? -v : v;
#endif
#else
  const u32 u = (d >> (8 * J)) & 0xFFu;
  const u32 e = (u >> 3) & 15u, m = u & 7u;
  float v = e ? __uint_as_float(((e + 120u) << 23) | (m << 20))
              : (float)m * 0.001953125f;
  return (u & 0x80u) ? -v : v;
#endif
}

__device__ __forceinline__ void gload_lds16(const void* g, void* l) {
  using gptr_t = const __attribute__((address_space(1))) uint32_t*;
  using lptr_t = __attribute__((address_space(3))) uint32_t*;
  __builtin_amdgcn_global_load_lds((gptr_t)(uintptr_t)g,
                                   (lptr_t)(uint32_t)(uintptr_t)l, 16, 0, 0);
}

// ---------------- f32 -> fp8 e4m3 bulk convert ----------------
__global__ __launch_bounds__(256) void k_f2b8(const float* __restrict__ in,
                                              u8* __restrict__ out, int n4) {
  for (int i = blockIdx.x * 256 + threadIdx.x; i < n4; i += gridDim.x * 256) {
    float4 v = ((const float4*)in)[i];
    u32 o = (u32)f2fp8(v.x) | ((u32)f2fp8(v.y) << 8) |
            ((u32)f2fp8(v.z) << 16) | ((u32)f2fp8(v.w) << 24);
    ((u32*)out)[i] = o;
  }
}

// ---------------- all 4 weight transposes (+bf16 convert) in one launch --------
__global__ __launch_bounds__(256) void k_prep_w(
    const float* __restrict__ wqkv, const float* __restrict__ wproj,
    const float* __restrict__ wfc1, const float* __restrict__ wfc2,
    u16* __restrict__ oqkv, u16* __restrict__ oproj,
    u16* __restrict__ ofc1, u16* __restrict__ ofc2) {
  int i = blockIdx.x * 256 + threadIdx.x;
  if (i < 196608) {                       // w_qkv 256x768 -> [768][256]
    int c = i >> 8, r = i & 255; oqkv[i] = f2b(wqkv[r * 768 + c]);
  } else if (i < 262144) {                // w_proj 256x256
    i -= 196608; int c = i >> 8, r = i & 255; oproj[i] = f2b(wproj[r * 256 + c]);
  } else if (i < 524288) {                // w_fc1 256x1024 -> [1024][256]
    i -= 262144; int c = i >> 8, r = i & 255; ofc1[i] = f2b(wfc1[r * 1024 + c]);
  } else {                                // w_fc2 1024x256 -> [256][1024]
    i -= 524288; int c = i >> 10, r = i & 1023; ofc2[i] = f2b(wfc2[r * 256 + c]);
  }
}

// ---------------- CPE gather + residual + LN1 (wave = 4 points) ----------------
__global__ __launch_bounds__(256) void k_cpe_ln1(
    const float* __restrict__ data, const int* __restrict__ nbr,
    const u8* __restrict__ datab, const float* __restrict__ w_cpe,
    const float* __restrict__ bn_g, const float* __restrict__ bn_b,
    const float* __restrict__ n1_g, const float* __restrict__ n1_b,
    float* __restrict__ xo, u16* __restrict__ ho) {
  __shared__ __align__(16) u16 sW[27 * 256];
  const int tid = threadIdx.x;
  for (int i = tid; i < 864; i += 256) {
    float4 a = ((const float4*)w_cpe)[i * 2];
    float4 b = ((const float4*)w_cpe)[i * 2 + 1];
    u32x4 o;
    o[0] = (u32)f2b(a.x) | ((u32)f2b(a.y) << 16);
    o[1] = (u32)f2b(a.z) | ((u32)f2b(a.w) << 16);
    o[2] = (u32)f2b(b.x) | ((u32)f2b(b.y) << 16);
    o[3] = (u32)f2b(b.z) | ((u32)f2b(b.w) << 16);
    ((u32x4*)sW)[i] = o;
  }
  __syncthreads();

  const int wv   = tid >> 6;
  const int lane = tid & 63;
  const int c0   = lane * 4;
  const int n0   = blockIdx.x * 16 + wv * 4;

  const float4 g4  = *(const float4*)(bn_g + c0);
  const float4 b4  = *(const float4*)(bn_b + c0);
  const float4 ng  = *(const float4*)(n1_g + c0);
  const float4 nb4 = *(const float4*)(n1_b + c0);

#pragma unroll 1
  for (int p = 0; p < 4; p++) {
    const int n = n0 + p;
    int myidx = 0;
    if (lane < 27) myidx = nbr[n * 27 + lane];

    u32 d[27];
#pragma unroll
    for (int j = 0; j < 27; j++) {
      const int idx = __builtin_amdgcn_readlane(myidx, j);
      d[j] = *(const u32*)(datab + (size_t)idx * CC + c0);
    }

    float a0 = 0.f, a1 = 0.f, a2 = 0.f, a3 = 0.f;
#pragma unroll
    for (int j = 0; j < 27; j++) {
      const u32x2 wp = *(const u32x2*)&sW[j * 256 + c0];
      a0 += fp82f<0>(d[j]) * b2f((u16)(wp[0] & 0xffff));
      a1 += fp82f<1>(d[j]) * b2f((u16)(wp[0] >> 16));
      a2 += fp82f<2>(d[j]) * b2f((u16)(wp[1] & 0xffff));
      a3 += fp82f<3>(d[j]) * b2f((u16)(wp[1] >> 16));
    }

    const float4 dv = *(const float4*)(data + (size_t)n * CC + c0);
    float x0 = dv.x + a0 * g4.x + b4.x;
    float x1 = dv.y + a1 * g4.y + b4.y;
    float x2 = dv.z + a2 * g4.z + b4.z;
    float x3 = dv.w + a3 * g4.w + b4.w;
    *(float4*)(xo + (size_t)n * CC + c0) = make_float4(x0, x1, x2, x3);

    float s  = x0 + x1 + x2 + x3;
    float s2 = x0 * x0 + x1 * x1 + x2 * x2 + x3 * x3;
#pragma unroll
    for (int m = 1; m <= 32; m <<= 1) { s += __shfl_xor(s, m); s2 += __shfl_xor(s2, m); }
    const float mean = s * (1.f / 256.f);
    const float var  = s2 * (1.f / 256.f) - mean * mean;
    const float inv  = rsqrtf(var + 1e-5f);

    u32x2 o;
    o[0] = (u32)f2b((x0 - mean) * inv * ng.x + nb4.x) |
           ((u32)f2b((x1 - mean) * inv * ng.y + nb4.y) << 16);
    o[1] = (u32)f2b((x2 - mean) * inv * ng.z + nb4.z) |
           ((u32)f2b((x3 - mean) * inv * ng.w + nb4.w) << 16);
    *(u32x2*)(ho + (size_t)n * CC + c0) = o;
  }
}

// ---------------- bf16 MFMA GEMM: C[M][ND] = A[M][KD] * Bt[ND][KD]^T -----------
// XCD-aware swizzle. EPI 0: bf16 = acc + bias; EPI 1: f32 += acc + bias;
// EPI 2: bf16 = gelu(acc + bias). EPI0/2 use an LDS-staged coalesced C-write
// ([128][136] u16 tile reusing the staging LDS; 8x u32x4 stores per thread).
template <int KD, int ND, int EPI>
__global__ __launch_bounds__(256) void k_gemm(const u16* __restrict__ A,
                                              const u16* __restrict__ Bt,
                                              const float* __restrict__ bias,
                                              u16* __restrict__ outb,
                                              float* __restrict__ outf) {
  constexpr int SMEM = (EPI == 1) ? 32768 : 34816;   // 128*136*2 for C-staging
  __shared__ __align__(16) char smem[SMEM];
  u16* As = (u16*)smem;
  u16* Bs = (u16*)(smem + 16384);
  const int tid = threadIdx.x;
  const int lane = tid & 63;
  const int wv = tid >> 6;
  const int wm = (wv >> 1) * 64;
  const int wn = (wv & 1) * 64;
  const int l15 = lane & 15;
  const int lhi = lane >> 4;

  const int gx = gridDim.x;
  const int bid = blockIdx.y * gx + blockIdx.x;
  const int cpx = (gx * gridDim.y) >> 3;
  const int swz = (bid & 7) * cpx + (bid >> 3);
  const int m0 = (swz / gx) * 128;
  const int n0 = (swz % gx) * 128;

  f32x4 acc[4][4] = {};

  for (int k0 = 0; k0 < KD; k0 += 64) {
#pragma unroll
    for (int i = 0; i < 4; i++) {
      const int off = i * 4096 + tid * 16;     // byte offset in 16KB tile
      const int row = off >> 7;                // 128B (=64 bf16) per row
      const int ke  = (off & 127) >> 1;        // element offset in K
      gload_lds16(A  + (size_t)(m0 + row) * KD + k0 + ke, (char*)As + off);
      gload_lds16(Bt + (size_t)(n0 + row) * KD + k0 + ke, (char*)Bs + off);
    }
    __syncthreads();
#pragma unroll
    for (int kk = 0; kk < 2; kk++) {
      bf16x8 fa[4], fb[4];
#pragma unroll
      for (int t = 0; t < 4; t++) {
        fa[t] = *(const bf16x8*)&As[(wm + t * 16 + l15) * 64 + kk * 32 + lhi * 8];
        fb[t] = *(const bf16x8*)&Bs[(wn + t * 16 + l15) * 64 + kk * 32 + lhi * 8];
      }
#pragma unroll
      for (int mi = 0; mi < 4; mi++)
#pragma unroll
        for (int ni = 0; ni < 4; ni++)
          acc[mi][ni] = __builtin_amdgcn_mfma_f32_16x16x32_bf16(fa[mi], fb[ni],
                                                                acc[mi][ni], 0, 0, 0);
    }
    __syncthreads();
  }

  if constexpr (EPI == 1) {
#pragma unroll
    for (int mi = 0; mi < 4; mi++) {
#pragma unroll
      for (int ni = 0; ni < 4; ni++) {
        const int col = n0 + wn + ni * 16 + l15;
        const float bc = bias[col];
#pragma unroll
        for (int r = 0; r < 4; r++) {
          const int row = m0 + wm + mi * 16 + lhi * 4 + r;
          outf[(size_t)row * ND + col] += acc[mi][ni][r] + bc;
        }
      }
    }
  } else {
    // stage C (+bias/+gelu, bf16) into [128][136] LDS tile, then coalesced store
    u16* OL = (u16*)smem;   // safe: final loop barrier drained all As/Bs reads
#pragma unroll
    for (int mi = 0; mi < 4; mi++) {
#pragma unroll
      for (int ni = 0; ni < 4; ni++) {
        const int lc = wn + ni * 16 + l15;
        const float bc = bias[n0 + lc];
#pragma unroll
        for (int r = 0; r < 4; r++) {
          float v = acc[mi][ni][r] + bc;
          if constexpr (EPI == 2)
            v = 0.5f * v * (1.0f + erff(v * 0.70710678118654752f));
          OL[(wm + mi * 16 + lhi * 4 + r) * 136 + lc] = f2b(v);
        }
      }
    }
    __syncthreads();
#pragma unroll
    for (int it = 0; it < 8; it++) {
      const int id = it * 256 + tid;           // 2048 chunks of 16B
      const int row = id >> 4;
      const int cc = (id & 15) * 8;
      u32x4 w = *(const u32x4*)&OL[row * 136 + cc];
      *(u32x4*)(outb + (size_t)(m0 + row) * ND + n0 + cc) = w;
    }
  }
}

// ---------------- proj GEMM + residual + LN2 fused ----------------
__global__ __launch_bounds__(256) void k_proj_ln2(
    const u16* __restrict__ A, const u16* __restrict__ Bt,
    const float* __restrict__ bias, float* __restrict__ xo,
    const float* __restrict__ n2g, const float* __restrict__ n2b,
    u16* __restrict__ h2) {
  __shared__ __align__(16) u16 As[128 * 64];
  __shared__ __align__(16) u16 Bs[256 * 64];
  const int tid = threadIdx.x;
  const int lane = tid & 63;
  const int wv = tid >> 6;
  const int l15 = lane & 15;
  const int g = lane >> 4;
  const int m0 = blockIdx.x * 128;
  const int wm = wv * 32;

  f32x4 acc[2][16] = {};

  for (int k0 = 0; k0 < 256; k0 += 64) {
#pragma unroll
    for (int i = 0; i < 4; i++) {
      const int off = i * 4096 + tid * 16;
      const int row = off >> 7, ke = (off & 127) >> 1;
      gload_lds16(A + (size_t)(m0 + row) * 256 + k0 + ke, (char*)As + off);
    }
#pragma unroll
    for (int i = 0; i < 8; i++) {
      const int off = i * 4096 + tid * 16;
      const int row = off >> 7, ke = (off & 127) >> 1;
      gload_lds16(Bt + (size_t)row * 256 + k0 + ke, (char*)Bs + off);
    }
    __syncthreads();
#pragma unroll
    for (int kk = 0; kk < 2; kk++) {
      bf16x8 fa[2];
#pragma unroll
      for (int t = 0; t < 2; t++)
        fa[t] = *(const bf16x8*)&As[(wm + t * 16 + l15) * 64 + kk * 32 + g * 8];
#pragma unroll
      for (int ni = 0; ni < 16; ni++) {
        bf16x8 fb = *(const bf16x8*)&Bs[(ni * 16 + l15) * 64 + kk * 32 + g * 8];
#pragma unroll
        for (int mi = 0; mi < 2; mi++)
          acc[mi][ni] = __builtin_amdgcn_mfma_f32_16x16x32_bf16(fa[mi], fb,
                                                                acc[mi][ni], 0, 0, 0);
      }
    }
    __syncthreads();
  }

#pragma unroll
  for (int mi = 0; mi < 2; mi++) {
#pragma unroll
    for (int r = 0; r < 4; r++) {
      const int row = m0 + wm + mi * 16 + g * 4 + r;
      float v[16];
      float s = 0.f, s2 = 0.f;
#pragma unroll
      for (int ni = 0; ni < 16; ni++) {
        const int col = ni * 16 + l15;
        float t = acc[mi][ni][r] + bias[col] + xo[(size_t)row * 256 + col];
        v[ni] = t; s += t; s2 += t * t;
      }
#pragma unroll
      for (int m = 1; m <= 8; m <<= 1) { s += __shfl_xor(s, m); s2 += __shfl_xor(s2, m); }
      const float mean = s * (1.f / 256.f);
      const float var  = s2 * (1.f / 256.f) - mean * mean;
      const float inv  = rsqrtf(var + 1e-5f);
#pragma unroll
      for (int ni = 0; ni < 16; ni++) {
        const int col = ni * 16 + l15;
        xo[(size_t)row * 256 + col] = v[ni];
        h2[(size_t)row * 256 + col] = f2b((v[ni] - mean) * inv * n2g[col] + n2b[col]);
      }
    }
  }
}

// ---------------- windowed attention with RPE (MFMA version) ----------------
__global__ __launch_bounds__(512, 4) void k_attn(const u16* __restrict__ qkv,
                                                 const int* __restrict__ rel_pos,
                                                 const float* __restrict__ pmask,
                                                 const float* __restrict__ rpet,
                                                 u16* __restrict__ out) {
  constexpr int HS = 1288;                      // u16 per head region (2576 B)
  __shared__ __align__(16) u16 smem[24 * HS + 2448];
  u16* sQ = smem;
  u16* sK = smem + 8 * HS;                      // overlaid by O_lds [32][264] later
  u16* sV = smem + 16 * HS;                     // V^T per head: [d][p], rows 40 u16
  float* sT = (float*)(smem + 24 * HS);         // [8][153]

  const int tid = threadIdx.x;
  const int nw  = blockIdx.x;
  const int w32 = nw * 32;

  for (int i = tid; i < 1224; i += 512) {
    int h = i / 153, ix = i - h * 153;
    sT[i] = rpet[ix * 8 + h];
  }
#pragma unroll
  for (int j = 0; j < 4; j++) {
    int id  = j * 512 + tid;
    int mat = id >> 10;                         // 0 = Q, 1 = K (wave-uniform)
    int id1 = id & 1023;
    int h = id1 >> 7, q = (id1 >> 2) & 31, s = id1 & 3;
    u32x4 v = *(const u32x4*)(qkv + (size_t)(w32 + q) * 768 + mat * 256 + h * 32 + s * 8);
    u16* dst = (mat ? sK : sQ) + h * HS + q * 40 + s * 8;
    *(u32x4*)dst = v;
  }
#pragma unroll
  for (int j = 0; j < 2; j++) {
    int id = j * 512 + tid;
    int p = id >> 5, dc = id & 31;
    u32x4 v = *(const u32x4*)(qkv + (size_t)(w32 + p) * 768 + 512 + dc * 8);
    const u16* pv = (const u16*)&v;
#pragma unroll
    for (int jj = 0; jj < 8; jj++) {
      int d = dc * 8 + jj;
      sV[(d >> 5) * HS + (d & 31) * 40 + p] = pv[jj];
    }
  }
  __syncthreads();

  const int h = tid >> 6;
  const int lane = tid & 63;
  const int g = lane >> 4, c = lane & 15;
  const f32x4 zero = {0.f, 0.f, 0.f, 0.f};

  bf16x8 fq[2], fk[2];
#pragma unroll
  for (int t = 0; t < 2; t++) {
    fq[t] = *(const bf16x8*)&sQ[h * HS + (t * 16 + c) * 40 + g * 8];
    fk[t] = *(const bf16x8*)&sK[h * HS + (t * 16 + c) * 40 + g * 8];
  }
  f32x4 S[2][2];
#pragma unroll
  for (int qt = 0; qt < 2; qt++)
#pragma unroll
    for (int kt = 0; kt < 2; kt++)
      S[qt][kt] = __builtin_amdgcn_mfma_f32_16x16x32_bf16(fq[qt], fk[kt], zero, 0, 0, 0);

  const float sc = 0.17677669529663687f;  // 32^-0.5
#pragma unroll
  for (int qt = 0; qt < 2; qt++) {
#pragma unroll
    for (int r = 0; r < 4; r++) {
      const int q = qt * 16 + g * 4 + r;
      const int* rp = rel_pos + ((size_t)(w32 + q) * 32) * 3;
      const float* pm = pmask + (size_t)(w32 + q) * 32;
      float v[2];
#pragma unroll
      for (int kt = 0; kt < 2; kt++) {
        const int k = kt * 16 + c;
        int r0 = rp[k * 3], r1 = rp[k * 3 + 1], r2 = rp[k * 3 + 2];
        r0 = min(max(r0, -25), 25);
        r1 = min(max(r1, -25), 25);
        r2 = min(max(r2, -25), 25);
        const float b = sT[h * 153 + 25 + r0] + sT[h * 153 + 76 + r1] +
                        sT[h * 153 + 127 + r2] + pm[k];
        v[kt] = S[qt][kt][r] * sc + b;
      }
      float m = fmaxf(v[0], v[1]);
#pragma unroll
      for (int d = 1; d <= 8; d <<= 1) m = fmaxf(m, __shfl_xor(m, d));
      const float e0 = __expf(v[0] - m);
      const float e1 = __expf(v[1] - m);
      float ssum = e0 + e1;
#pragma unroll
      for (int d = 1; d <= 8; d <<= 1) ssum += __shfl_xor(ssum, d);
      const float inv = 1.0f / ssum;
      sQ[h * HS + q * 40 + c]      = f2b(e0 * inv);
      sQ[h * HS + q * 40 + 16 + c] = f2b(e1 * inv);
    }
  }
  __builtin_amdgcn_sched_barrier(0);  // P writes stay before P-fragment reads

  bf16x8 fp[2], fv[2];
#pragma unroll
  for (int t = 0; t < 2; t++) {
    fp[t] = *(const bf16x8*)&sQ[h * HS + (t * 16 + c) * 40 + g * 8];
    fv[t] = *(const bf16x8*)&sV[h * HS + (t * 16 + c) * 40 + g * 8];
  }
  f32x4 OT[2][2];
#pragma unroll
  for (int dt = 0; dt < 2; dt++)
#pragma unroll
    for (int qt = 0; qt < 2; qt++)
      OT[dt][qt] = __builtin_amdgcn_mfma_f32_16x16x32_bf16(fv[dt], fp[qt], zero, 0, 0, 0);

  __syncthreads();                     // all waves done reading K: reuse sK as O_lds
  u16* OL = sK;                        // [32 rows][264 u16]
#pragma unroll
  for (int dt = 0; dt < 2; dt++)
#pragma unroll
    for (int qt = 0; qt < 2; qt++)
#pragma unroll
      for (int r = 0; r < 4; r++) {
        const int d = dt * 16 + g * 4 + r, q = qt * 16 + c;
        OL[q * 264 + h * 32 + d] = f2b(OT[dt][qt][r]);
      }
  __syncthreads();

  {
    const int q = tid >> 4, ch = tid & 15;
    u32x4 w0 = *(const u32x4*)&OL[q * 264 + ch * 16];
    u32x4 w1 = *(const u32x4*)&OL[q * 264 + ch * 16 + 8];
    u16* ob = out + (size_t)(w32 + q) * 256 + ch * 16;
    *(u32x4*)ob = w0;
    *((u32x4*)ob + 1) = w1;
  }
}

extern "C" void kernel_launch(void* const* d_in, const int* in_sizes, int n_in,
                              void* d_out, int out_size, void* d_ws, size_t ws_size,
                              hipStream_t stream) {
  const float* data   = (const float*)d_in[0];
  const int*   nbr    = (const int*)d_in[1];
  const int*   relpos = (const int*)d_in[2];
  const float* pmask  = (const float*)d_in[3];
  const float* w_cpe  = (const float*)d_in[4];
  const float* bn_g   = (const float*)d_in[5];
  const float* bn_b   = (const float*)d_in[6];
  const float* n1_g   = (const float*)d_in[7];
  const float* n1_b   = (const float*)d_in[8];
  const float* w_qkv  = (const float*)d_in[9];
  const float* b_qkv  = (const float*)d_in[10];
  const float* w_proj = (const float*)d_in[11];
  const float* b_proj = (const float*)d_in[12];
  const float* rpet   = (const float*)d_in[13];
  const float* n2_g   = (const float*)d_in[14];
  const float* n2_b   = (const float*)d_in[15];
  const float* w_fc1  = (const float*)d_in[16];
  const float* b_fc1  = (const float*)d_in[17];
  const float* w_fc2  = (const float*)d_in[18];
  const float* b_fc2  = (const float*)d_in[19];
  float* xout = (float*)d_out;  // residual stream x lives in d_out (f32)

  char* pw = (char*)d_ws;
  u16* buf1 = (u16*)pw; pw += (size_t)NPT * 1024 * 2;  // fp8 data / qkv / hidden bf16
  u16* buf2 = (u16*)pw; pw += (size_t)NPT * 256 * 2;   // h / attn_out / h2
  u16* wqkvT = (u16*)pw; pw += 768 * 256 * 2;
  u16* wprojT = (u16*)pw; pw += 256 * 256 * 2;
  u16* wfc1T = (u16*)pw; pw += 1024 * 256 * 2;
  u16* wfc2T = (u16*)pw; pw += 256 * 1024 * 2;
  u8* data8 = (u8*)buf1;  // 32 MB fp8 copy, consumed before buf1 is reused by QKV

  // prep: fp8 copy of data (for CPE gathers), transposed bf16 weights
  k_f2b8<<<2048, 256, 0, stream>>>(data, data8, NPT * 256 / 4);
  k_prep_w<<<3072, 256, 0, stream>>>(w_qkv, w_proj, w_fc1, w_fc2,
                                     wqkvT, wprojT, wfc1T, wfc2T);

  // CPE + residual + LN1:  x -> d_out(f32), h -> buf2(bf16)
  k_cpe_ln1<<<NPT / 16, 256, 0, stream>>>(data, nbr, data8, w_cpe, bn_g, bn_b,
                                          n1_g, n1_b, xout, buf2);
  // QKV = h @ w_qkv + b  -> buf1 (bf16, N x 768)
  k_gemm<256, 768, 0><<<dim3(6, 1024), 256, 0, stream>>>(buf2, wqkvT, b_qkv, buf1, nullptr);
  // attention -> buf2 (bf16, N x 256)
  k_attn<<<NWIN, 512, 0, stream>>>(buf1, relpos, pmask, rpet, buf2);
  // x += attn_out @ w_proj + b; h2 = LN2(x) -> buf2
  k_proj_ln2<<<1024, 256, 0, stream>>>(buf2, wprojT, b_proj, xout, n2_g, n2_b, buf2);
  // hidden = gelu(h2 @ w_fc1 + b) -> buf1 (bf16, N x 1024)
  k_gemm<256, 1024, 2><<<dim3(8, 1024), 256, 0, stream>>>(buf2, wfc1T, b_fc1, buf1, nullptr);
  // x += hidden @ w_fc2 + b   (final output in d_out)
  k_gemm<1024, 256, 1><<<dim3(2, 1024), 256, 0, stream>>>(buf1, wfc2T, b_fc2, nullptr, xout);
}